// Round 3
// baseline (615.722 us; speedup 1.0000x reference)
//
#include <hip/hip_runtime.h>

#define DIM 768
#define TD 2304
#define NB 8
#define NS 4096
#define NE 6

// ws layout (float offsets)
#define OFF_QCATT  0        // [3][18][768] = 41472  rows: 0-5 Q, 6-11 P, 12-17 A1 (colmean fold)
#define OFF_A2F    41472    // [2304][6]   = 13824   delta-mean fold
#define OFF_GFULL  55296    // [224][6]
#define OFF_CB0    56640    // [16]
#define OFF_ACCSUM 56656    // [8][6] + pad = 64
#define OFF_CONSTB 56720    // [8][6] + pad
#define OFF_QP     56832    // [3][32768][12] = 1179648

// ---------------- kernel A: fold global path (Gfull, cb0) ----------------
__global__ __launch_bounds__(256) void k_fold0(
    const float* __restrict__ Wglob, const float* __restrict__ bglob,
    const float* __restrict__ Wroute, const float* __restrict__ broute,
    const float* __restrict__ bspat, const float* __restrict__ btemp,
    const float* __restrict__ bsync,
    float* __restrict__ Gfull, float* __restrict__ cb0)
{
    __shared__ float lwr[288 * NE];
    __shared__ float lgf[224 * NE];
    const int t = threadIdx.x;
    for (int i = t; i < 288 * NE; i += 256) lwr[i] = Wroute[i];
    __syncthreads();
    if (t < 224) {
        float g[NE] = {0, 0, 0, 0, 0, 0};
        for (int o = 0; o < 64; ++o) {
            const float w = Wglob[t * 64 + o];
            #pragma unroll
            for (int e = 0; e < NE; ++e) g[e] += w * lwr[(224 + o) * NE + e];
        }
        #pragma unroll
        for (int e = 0; e < NE; ++e) { Gfull[t * NE + e] = g[e]; lgf[t * NE + e] = g[e]; }
    }
    __syncthreads();
    if (t < NE) {
        float a = broute[t];
        for (int o = 0; o < 64; ++o)  a += bglob[o] * lwr[(224 + o) * NE + t];
        for (int o = 0; o < 128; ++o) a += bspat[o] * (lwr[o * NE + t] + lgf[o * NE + t]);
        for (int o = 0; o < 64; ++o)  a += btemp[o] * (lwr[(128 + o) * NE + t] + lgf[(128 + o) * NE + t]);
        for (int o = 0; o < 32; ++o)  a += bsync[o] * (lwr[(192 + o) * NE + t] + lgf[(192 + o) * NE + t]);
        cb0[t] = a;
    }
}

// ---------------- kernel B: fold per-column coefficients ----------------
__global__ __launch_bounds__(256) void k_fold(
    const float* __restrict__ Wspat, const float* __restrict__ Wtemp,
    const float* __restrict__ Wsync, const float* __restrict__ Wroute,
    const float* __restrict__ Gfull,
    float* __restrict__ QcatT, float* __restrict__ A2F)
{
    __shared__ float lwr[224 * NE];
    __shared__ float lgf[224 * NE];
    const int t = threadIdx.x;
    for (int i = t; i < 224 * NE; i += 256) { lwr[i] = Wroute[i]; lgf[i] = Gfull[i]; }
    __syncthreads();
    const int d = blockIdx.x * 256 + t;          // exactly 2304 threads
    const int st = d / DIM, dd = d - st * DIM;

    float p[NE] = {0, 0, 0, 0, 0, 0}, a2[NE] = {0, 0, 0, 0, 0, 0};
    for (int o = 0; o < 64; ++o) {
        const float w = Wtemp[d * 64 + o];
        #pragma unroll
        for (int e = 0; e < NE; ++e) {
            p[e]  += w * lwr[(128 + o) * NE + e];
            a2[e] += w * lgf[(128 + o) * NE + e];
        }
    }
    float qq[NE], a1[NE];
    #pragma unroll
    for (int e = 0; e < NE; ++e) { qq[e] = p[e]; a1[e] = 0.f; }
    for (int o = 0; o < 128; ++o) {
        const float w = Wspat[d * 128 + o];
        #pragma unroll
        for (int e = 0; e < NE; ++e) {
            qq[e] += w * lwr[o * NE + e];
            a1[e] += w * lgf[o * NE + e];
        }
    }
    if (st != 0) {
        const float sg = (st == 1) ? 1.f : -1.f;
        for (int o = 0; o < 32; ++o) {
            const float w = sg * Wsync[dd * 32 + o];
            #pragma unroll
            for (int e = 0; e < NE; ++e) {
                qq[e] += w * lwr[(192 + o) * NE + e];
                a1[e] += w * lgf[(192 + o) * NE + e];
            }
        }
    }
    #pragma unroll
    for (int e = 0; e < NE; ++e) {
        QcatT[(st * 18 + e) * DIM + dd]      = qq[e];
        QcatT[(st * 18 + 6 + e) * DIM + dd]  = p[e];
        QcatT[(st * 18 + 12 + e) * DIM + dd] = a1[e];
        A2F[d * NE + e] = a2[e];
    }
}

// ---------------- kernel C: main streaming pass ----------------
// grid = 8b * 3st * 32rg = 768 blocks; 256 thr = 4 waves; wave = 32 rows.
// lane: r8=l>>3 (4-row group), c4=l&7 (16B col quad). 24 col-steps of 32.
// Pure-FMA hot loop: no LDS, no barriers, no cross-lane ops.

#define LDX(n0, n1, n2, n3, CO)                          \
    n0 = *(const float4*)(xq + (CO));                    \
    n1 = *(const float4*)(xq + (CO) + DIM);              \
    n2 = *(const float4*)(xq + (CO) + 2 * DIM);          \
    n3 = *(const float4*)(xq + (CO) + 3 * DIM);

#define STEP(n0, n1, n2, n3, CO)                                           \
  {                                                                        \
    _Pragma("unroll")                                                      \
    for (int r = 0; r < 12; ++r) {                                         \
      const float4 cf = *(const float4*)(cq + r * DIM + (CO));             \
      acc[0][r] += n0.x * cf.x; acc[0][r] += n0.y * cf.y;                  \
      acc[0][r] += n0.z * cf.z; acc[0][r] += n0.w * cf.w;                  \
      acc[1][r] += n1.x * cf.x; acc[1][r] += n1.y * cf.y;                  \
      acc[1][r] += n1.z * cf.z; acc[1][r] += n1.w * cf.w;                  \
      acc[2][r] += n2.x * cf.x; acc[2][r] += n2.y * cf.y;                  \
      acc[2][r] += n2.z * cf.z; acc[2][r] += n2.w * cf.w;                  \
      acc[3][r] += n3.x * cf.x; acc[3][r] += n3.y * cf.y;                  \
      acc[3][r] += n3.z * cf.z; acc[3][r] += n3.w * cf.w;                  \
    }                                                                      \
    const float sx = n0.x + n1.x + n2.x + n3.x;                            \
    const float sy = n0.y + n1.y + n2.y + n3.y;                            \
    const float sz = n0.z + n1.z + n2.z + n3.z;                            \
    const float sw = n0.w + n1.w + n2.w + n3.w;                            \
    _Pragma("unroll")                                                      \
    for (int e = 0; e < 6; ++e) {                                          \
      const float4 af = *(const float4*)(cq + (12 + e) * DIM + (CO));      \
      acca[e] += sx * af.x; acca[e] += sy * af.y;                          \
      acca[e] += sz * af.z; acca[e] += sw * af.w;                          \
    }                                                                      \
  }

__global__ __launch_bounds__(256, 3) void k_main(
    const float* __restrict__ xt, const float* __restrict__ xa, const float* __restrict__ xv,
    const float* __restrict__ QcatT, float* __restrict__ accsum, float* __restrict__ qp)
{
    const int t = threadIdx.x;
    const int w = t >> 6, l = t & 63;
    const int r8 = l >> 3, c4 = l & 7;
    const int bid = blockIdx.x;
    const int rg = bid & 31;
    const int st = (bid >> 5) % 3;
    const int b  = bid / 96;

    const float* X = (st == 0) ? xt : ((st == 1) ? xa : xv);
    const int row0 = rg * 128 + w * 32 + r8 * 4;
    const float* xq = X + (b * NS + row0) * DIM + c4 * 4;
    const float* cq = QcatT + st * 18 * DIM + c4 * 4;

    float acc[4][12];
    #pragma unroll
    for (int k = 0; k < 4; ++k)
        #pragma unroll
        for (int r = 0; r < 12; ++r) acc[k][r] = 0.f;
    float acca[NE] = {0, 0, 0, 0, 0, 0};

    float4 va0, va1, va2, va3, vb0, vb1, vb2, vb3;
    LDX(va0, va1, va2, va3, 0)
    LDX(vb0, vb1, vb2, vb3, 32)

    for (int j = 0; j < 24; j += 2) {
        STEP(va0, va1, va2, va3, 0)
        if (j + 2 < 24) { LDX(va0, va1, va2, va3, 64) }
        STEP(vb0, vb1, vb2, vb3, 32)
        if (j + 3 < 24) { LDX(vb0, vb1, vb2, vb3, 96) }
        xq += 64; cq += 64;
    }

    // reduce q/p partials across the 8 c4 lanes
    #pragma unroll
    for (int k = 0; k < 4; ++k)
        #pragma unroll
        for (int r = 0; r < 12; ++r) {
            float v = acc[k][r];
            v += __shfl_xor(v, 1, 64);
            v += __shfl_xor(v, 2, 64);
            v += __shfl_xor(v, 4, 64);
            acc[k][r] = v;
        }
    if (c4 == 0) {
        float* dst = qp + ((st * NB + b) * NS + row0) * 12;
        #pragma unroll
        for (int k = 0; k < 4; ++k) {
            *(float4*)(dst + k * 12 + 0) = make_float4(acc[k][0], acc[k][1], acc[k][2],  acc[k][3]);
            *(float4*)(dst + k * 12 + 4) = make_float4(acc[k][4], acc[k][5], acc[k][6],  acc[k][7]);
            *(float4*)(dst + k * 12 + 8) = make_float4(acc[k][8], acc[k][9], acc[k][10], acc[k][11]);
        }
    }

    // reduce global-path partials across the whole wave, one atomic set per wave
    #pragma unroll
    for (int e = 0; e < NE; ++e) {
        float v = acca[e];
        #pragma unroll
        for (int m = 1; m < 64; m <<= 1) v += __shfl_xor(v, m, 64);
        acca[e] = v;
    }
    if (l == 0) {
        #pragma unroll
        for (int e = 0; e < NE; ++e) atomicAdd(&accsum[b * NE + e], acca[e]);
    }
}

// ---------------- kernel D: per-batch global constant ----------------
__global__ __launch_bounds__(256) void k_const(
    const float* __restrict__ xt, const float* __restrict__ xa, const float* __restrict__ xv,
    const float* __restrict__ accsum, const float* __restrict__ A2F,
    const float* __restrict__ cb0, float* __restrict__ constb)
{
    const int b = blockIdx.x, t = threadIdx.x;
    const float* Xs[3] = { xt, xa, xv };
    float acc[NE] = {0, 0, 0, 0, 0, 0};
    for (int f = t; f < TD; f += 256) {
        const int st = f / DIM, dd = f - st * DIM;
        const float* Xp = Xs[st] + b * NS * DIM;
        const float dm = Xp[(NS - 1) * DIM + dd] - Xp[dd];
        const float* Ap = A2F + f * NE;
        #pragma unroll
        for (int e = 0; e < NE; ++e) acc[e] += dm * Ap[e];
    }
    #pragma unroll
    for (int e = 0; e < NE; ++e)
        for (int m = 1; m < 64; m <<= 1) acc[e] += __shfl_xor(acc[e], m, 64);
    __shared__ float wred[4][NE];
    if ((t & 63) == 0) {
        #pragma unroll
        for (int e = 0; e < NE; ++e) wred[t >> 6][e] = acc[e];
    }
    __syncthreads();
    if (t < NE) {
        const float inv = 1.f / 4096.f;
        const float dsum = wred[0][t] + wred[1][t] + wred[2][t] + wred[3][t];
        constb[b * NE + t] = cb0[t] + accsum[b * NE + t] * inv + dsum * inv;
    }
}

// ---------------- kernel E: combine q - shifted p + const ----------------
__global__ __launch_bounds__(256) void k_add(
    const float* __restrict__ qp, const float* __restrict__ constb, float* __restrict__ out)
{
    const int row = blockIdx.x * 256 + threadIdx.x;   // 32768 rows exact
    const int b = row >> 12, s = row & (NS - 1);
    const int rowp = (s == 0) ? row : row - 1;
    float o[NE];
    #pragma unroll
    for (int e = 0; e < NE; ++e) o[e] = constb[b * NE + e];
    #pragma unroll
    for (int st = 0; st < 3; ++st) {
        const float* qr = qp + (st * NB * NS + row) * 12;
        const float* pr = qp + (st * NB * NS + rowp) * 12;
        #pragma unroll
        for (int e = 0; e < NE; ++e) o[e] += qr[e] - pr[6 + e];
    }
    float* op = out + row * NE;
    #pragma unroll
    for (int e = 0; e < NE; ++e) op[e] = o[e];
}

extern "C" void kernel_launch(void* const* d_in, const int* in_sizes, int n_in,
                              void* d_out, int out_size, void* d_ws, size_t ws_size,
                              hipStream_t stream)
{
    const float* xt     = (const float*)d_in[0];
    const float* xa     = (const float*)d_in[1];
    const float* xv     = (const float*)d_in[2];
    const float* Wspat  = (const float*)d_in[3];
    const float* bspat  = (const float*)d_in[4];
    const float* Wtemp  = (const float*)d_in[5];
    const float* btemp  = (const float*)d_in[6];
    const float* Wsync  = (const float*)d_in[7];
    const float* bsync  = (const float*)d_in[8];
    const float* Wglob  = (const float*)d_in[9];
    const float* bglob  = (const float*)d_in[10];
    const float* Wroute = (const float*)d_in[11];
    const float* broute = (const float*)d_in[12];
    float* out = (float*)d_out;

    float* ws     = (float*)d_ws;
    float* QcatT  = ws + OFF_QCATT;
    float* A2F    = ws + OFF_A2F;
    float* Gfull  = ws + OFF_GFULL;
    float* cb0    = ws + OFF_CB0;
    float* accsum = ws + OFF_ACCSUM;
    float* constb = ws + OFF_CONSTB;
    float* qp     = ws + OFF_QP;

    hipMemsetAsync(accsum, 0, 64 * sizeof(float), stream);
    k_fold0<<<1, 256, 0, stream>>>(Wglob, bglob, Wroute, broute, bspat, btemp, bsync, Gfull, cb0);
    k_fold<<<9, 256, 0, stream>>>(Wspat, Wtemp, Wsync, Wroute, Gfull, QcatT, A2F);
    k_main<<<768, 256, 0, stream>>>(xt, xa, xv, QcatT, accsum, qp);
    k_const<<<8, 256, 0, stream>>>(xt, xa, xv, accsum, A2F, cb0, constb);
    k_add<<<128, 256, 0, stream>>>(qp, constb, out);
}

// Round 4
// 346.750 us; speedup vs baseline: 1.7757x; 1.7757x over previous
//
#include <hip/hip_runtime.h>

#define DIM 768
#define TD 2304
#define NB 8
#define NS 4096
#define NE 6

// ws layout (float offsets)
#define OFF_QCATT  0        // [3][18][768] = 41472  rows: 0-5 Q, 6-11 P, 12-17 A1 (colmean fold)
#define OFF_A2F    41472    // [2304][6]   = 13824   delta-mean fold
#define OFF_GFULL  55296    // [224][6]
#define OFF_CB0    56640    // [16]
#define OFF_ACCSUM 56656    // [8][6] + pad = 64
#define OFF_CONSTB 56720    // [8][6] + pad
#define OFF_QP     56832    // [3][32768][12] = 1179648

// ---------------- kernel A: fold global path (Gfull, cb0) ----------------
__global__ __launch_bounds__(256) void k_fold0(
    const float* __restrict__ Wglob, const float* __restrict__ bglob,
    const float* __restrict__ Wroute, const float* __restrict__ broute,
    const float* __restrict__ bspat, const float* __restrict__ btemp,
    const float* __restrict__ bsync,
    float* __restrict__ Gfull, float* __restrict__ cb0)
{
    __shared__ float lwr[288 * NE];
    __shared__ float lgf[224 * NE];
    const int t = threadIdx.x;
    for (int i = t; i < 288 * NE; i += 256) lwr[i] = Wroute[i];
    __syncthreads();
    if (t < 224) {
        float g[NE] = {0, 0, 0, 0, 0, 0};
        for (int o = 0; o < 64; ++o) {
            const float w = Wglob[t * 64 + o];
            #pragma unroll
            for (int e = 0; e < NE; ++e) g[e] += w * lwr[(224 + o) * NE + e];
        }
        #pragma unroll
        for (int e = 0; e < NE; ++e) { Gfull[t * NE + e] = g[e]; lgf[t * NE + e] = g[e]; }
    }
    __syncthreads();
    if (t < NE) {
        float a = broute[t];
        for (int o = 0; o < 64; ++o)  a += bglob[o] * lwr[(224 + o) * NE + t];
        for (int o = 0; o < 128; ++o) a += bspat[o] * (lwr[o * NE + t] + lgf[o * NE + t]);
        for (int o = 0; o < 64; ++o)  a += btemp[o] * (lwr[(128 + o) * NE + t] + lgf[(128 + o) * NE + t]);
        for (int o = 0; o < 32; ++o)  a += bsync[o] * (lwr[(192 + o) * NE + t] + lgf[(192 + o) * NE + t]);
        cb0[t] = a;
    }
}

// ---------------- kernel B: fold per-column coefficients ----------------
__global__ __launch_bounds__(256) void k_fold(
    const float* __restrict__ Wspat, const float* __restrict__ Wtemp,
    const float* __restrict__ Wsync, const float* __restrict__ Wroute,
    const float* __restrict__ Gfull,
    float* __restrict__ QcatT, float* __restrict__ A2F)
{
    __shared__ float lwr[224 * NE];
    __shared__ float lgf[224 * NE];
    const int t = threadIdx.x;
    for (int i = t; i < 224 * NE; i += 256) { lwr[i] = Wroute[i]; lgf[i] = Gfull[i]; }
    __syncthreads();
    const int d = blockIdx.x * 256 + t;          // exactly 2304 threads
    const int st = d / DIM, dd = d - st * DIM;

    float p[NE] = {0, 0, 0, 0, 0, 0}, a2[NE] = {0, 0, 0, 0, 0, 0};
    for (int o = 0; o < 64; ++o) {
        const float w = Wtemp[d * 64 + o];
        #pragma unroll
        for (int e = 0; e < NE; ++e) {
            p[e]  += w * lwr[(128 + o) * NE + e];
            a2[e] += w * lgf[(128 + o) * NE + e];
        }
    }
    float qq[NE], a1[NE];
    #pragma unroll
    for (int e = 0; e < NE; ++e) { qq[e] = p[e]; a1[e] = 0.f; }
    for (int o = 0; o < 128; ++o) {
        const float w = Wspat[d * 128 + o];
        #pragma unroll
        for (int e = 0; e < NE; ++e) {
            qq[e] += w * lwr[o * NE + e];
            a1[e] += w * lgf[o * NE + e];
        }
    }
    if (st != 0) {
        const float sg = (st == 1) ? 1.f : -1.f;
        for (int o = 0; o < 32; ++o) {
            const float w = sg * Wsync[dd * 32 + o];
            #pragma unroll
            for (int e = 0; e < NE; ++e) {
                qq[e] += w * lwr[(192 + o) * NE + e];
                a1[e] += w * lgf[(192 + o) * NE + e];
            }
        }
    }
    #pragma unroll
    for (int e = 0; e < NE; ++e) {
        QcatT[(st * 18 + e) * DIM + dd]      = qq[e];
        QcatT[(st * 18 + 6 + e) * DIM + dd]  = p[e];
        QcatT[(st * 18 + 12 + e) * DIM + dd] = a1[e];
        A2F[d * NE + e] = a2[e];
    }
}

// ---------------- kernel C: main streaming pass ----------------
// grid = 8b * 3st * 64rg = 1536 blocks; 256 thr = 4 waves; wave = 16 rows.
// lane: r8=l>>3 (2-row group), h=(l>>2)&1 (output half), c4=l&3 (16B col quad).
// 48 col-steps of 16. Per-thread accs: o0[6], o1[6], ga[3] (promotable sizes).

#define LDX2(m0, m1, CO)                                 \
    m0 = *(const float4*)(xq + (CO));                    \
    m1 = *(const float4*)(xq + (CO) + DIM);

#define STEP2(m0, m1, CO)                                                  \
  {                                                                        \
    _Pragma("unroll")                                                      \
    for (int e = 0; e < 6; ++e) {                                          \
      const float4 cf = *(const float4*)(cq + e * DIM + (CO));             \
      o0[e] += m0.x * cf.x; o0[e] += m0.y * cf.y;                          \
      o0[e] += m0.z * cf.z; o0[e] += m0.w * cf.w;                          \
      o1[e] += m1.x * cf.x; o1[e] += m1.y * cf.y;                          \
      o1[e] += m1.z * cf.z; o1[e] += m1.w * cf.w;                          \
    }                                                                      \
    const float sx = m0.x + m1.x;                                          \
    const float sy = m0.y + m1.y;                                          \
    const float sz = m0.z + m1.z;                                          \
    const float sw = m0.w + m1.w;                                          \
    _Pragma("unroll")                                                      \
    for (int e = 0; e < 3; ++e) {                                          \
      const float4 af = *(const float4*)(ca + e * DIM + (CO));             \
      ga[e] += sx * af.x; ga[e] += sy * af.y;                              \
      ga[e] += sz * af.z; ga[e] += sw * af.w;                              \
    }                                                                      \
  }

__global__ __launch_bounds__(256, 4) void k_main(
    const float* __restrict__ xt, const float* __restrict__ xa, const float* __restrict__ xv,
    const float* __restrict__ QcatT, float* __restrict__ accsum, float* __restrict__ qp)
{
    const int t = threadIdx.x;
    const int w = t >> 6, l = t & 63;
    const int r8 = l >> 3;
    const int h  = (l >> 2) & 1;
    const int c4 = l & 3;
    const int bid = blockIdx.x;
    const int rg = bid & 63;
    const int st = (bid >> 6) % 3;
    const int b  = bid / 192;

    const float* X = (st == 0) ? xt : ((st == 1) ? xa : xv);
    const int row0 = rg * 64 + w * 16 + r8 * 2;
    const float* xq = X + (b * NS + row0) * DIM + c4 * 4;
    const float* cq = QcatT + (st * 18 + h * 6) * DIM + c4 * 4;
    const float* ca = QcatT + (st * 18 + 12 + h * 3) * DIM + c4 * 4;

    float o0[6] = {0, 0, 0, 0, 0, 0};
    float o1[6] = {0, 0, 0, 0, 0, 0};
    float ga[3] = {0, 0, 0};

    float4 va0, va1, vb0, vb1;
    LDX2(va0, va1, 0)
    LDX2(vb0, vb1, 16)

    for (int j = 0; j < 48; j += 2) {
        STEP2(va0, va1, 0)
        if (j + 2 < 48) { LDX2(va0, va1, 32) }
        STEP2(vb0, vb1, 16)
        if (j + 3 < 48) { LDX2(vb0, vb1, 48) }
        xq += 32; cq += 32; ca += 32;
    }

    // reduce across the 4 c4 lanes
    #pragma unroll
    for (int e = 0; e < 6; ++e) {
        float v0 = o0[e];
        v0 += __shfl_xor(v0, 1, 64);
        v0 += __shfl_xor(v0, 2, 64);
        o0[e] = v0;
        float v1 = o1[e];
        v1 += __shfl_xor(v1, 1, 64);
        v1 += __shfl_xor(v1, 2, 64);
        o1[e] = v1;
    }
    if (c4 == 0) {
        float* dst = qp + ((st * NB + b) * NS + row0) * 12 + h * 6;
        *(float2*)(dst + 0) = make_float2(o0[0], o0[1]);
        *(float2*)(dst + 2) = make_float2(o0[2], o0[3]);
        *(float2*)(dst + 4) = make_float2(o0[4], o0[5]);
        *(float2*)(dst + 12) = make_float2(o1[0], o1[1]);
        *(float2*)(dst + 14) = make_float2(o1[2], o1[3]);
        *(float2*)(dst + 16) = make_float2(o1[4], o1[5]);
    }

    // reduce global-path partials over c4 (1,2) and r8 (8,16,32); keep h split
    #pragma unroll
    for (int e = 0; e < 3; ++e) {
        float v = ga[e];
        v += __shfl_xor(v, 1, 64);
        v += __shfl_xor(v, 2, 64);
        v += __shfl_xor(v, 8, 64);
        v += __shfl_xor(v, 16, 64);
        v += __shfl_xor(v, 32, 64);
        ga[e] = v;
    }
    if ((l & 59) == 0) {      // lanes 0 (h=0) and 4 (h=1)
        #pragma unroll
        for (int e = 0; e < 3; ++e)
            atomicAdd(&accsum[b * NE + h * 3 + e], ga[e]);
    }
}

// ---------------- kernel D: per-batch global constant ----------------
__global__ __launch_bounds__(256) void k_const(
    const float* __restrict__ xt, const float* __restrict__ xa, const float* __restrict__ xv,
    const float* __restrict__ accsum, const float* __restrict__ A2F,
    const float* __restrict__ cb0, float* __restrict__ constb)
{
    const int b = blockIdx.x, t = threadIdx.x;
    const float* Xs[3] = { xt, xa, xv };
    float acc[NE] = {0, 0, 0, 0, 0, 0};
    for (int f = t; f < TD; f += 256) {
        const int st = f / DIM, dd = f - st * DIM;
        const float* Xp = Xs[st] + b * NS * DIM;
        const float dm = Xp[(NS - 1) * DIM + dd] - Xp[dd];
        const float* Ap = A2F + f * NE;
        #pragma unroll
        for (int e = 0; e < NE; ++e) acc[e] += dm * Ap[e];
    }
    #pragma unroll
    for (int e = 0; e < NE; ++e)
        for (int m = 1; m < 64; m <<= 1) acc[e] += __shfl_xor(acc[e], m, 64);
    __shared__ float wred[4][NE];
    if ((t & 63) == 0) {
        #pragma unroll
        for (int e = 0; e < NE; ++e) wred[t >> 6][e] = acc[e];
    }
    __syncthreads();
    if (t < NE) {
        const float inv = 1.f / 4096.f;
        const float dsum = wred[0][t] + wred[1][t] + wred[2][t] + wred[3][t];
        constb[b * NE + t] = cb0[t] + accsum[b * NE + t] * inv + dsum * inv;
    }
}

// ---------------- kernel E: combine q - shifted p + const ----------------
__global__ __launch_bounds__(256) void k_add(
    const float* __restrict__ qp, const float* __restrict__ constb, float* __restrict__ out)
{
    const int row = blockIdx.x * 256 + threadIdx.x;   // 32768 rows exact
    const int b = row >> 12, s = row & (NS - 1);
    const int rowp = (s == 0) ? row : row - 1;
    float o[NE];
    #pragma unroll
    for (int e = 0; e < NE; ++e) o[e] = constb[b * NE + e];
    #pragma unroll
    for (int st = 0; st < 3; ++st) {
        const float* qr = qp + (st * NB * NS + row) * 12;
        const float* pr = qp + (st * NB * NS + rowp) * 12;
        #pragma unroll
        for (int e = 0; e < NE; ++e) o[e] += qr[e] - pr[6 + e];
    }
    float* op = out + row * NE;
    #pragma unroll
    for (int e = 0; e < NE; ++e) op[e] = o[e];
}

extern "C" void kernel_launch(void* const* d_in, const int* in_sizes, int n_in,
                              void* d_out, int out_size, void* d_ws, size_t ws_size,
                              hipStream_t stream)
{
    const float* xt     = (const float*)d_in[0];
    const float* xa     = (const float*)d_in[1];
    const float* xv     = (const float*)d_in[2];
    const float* Wspat  = (const float*)d_in[3];
    const float* bspat  = (const float*)d_in[4];
    const float* Wtemp  = (const float*)d_in[5];
    const float* btemp  = (const float*)d_in[6];
    const float* Wsync  = (const float*)d_in[7];
    const float* bsync  = (const float*)d_in[8];
    const float* Wglob  = (const float*)d_in[9];
    const float* bglob  = (const float*)d_in[10];
    const float* Wroute = (const float*)d_in[11];
    const float* broute = (const float*)d_in[12];
    float* out = (float*)d_out;

    float* ws     = (float*)d_ws;
    float* QcatT  = ws + OFF_QCATT;
    float* A2F    = ws + OFF_A2F;
    float* Gfull  = ws + OFF_GFULL;
    float* cb0    = ws + OFF_CB0;
    float* accsum = ws + OFF_ACCSUM;
    float* constb = ws + OFF_CONSTB;
    float* qp     = ws + OFF_QP;

    hipMemsetAsync(accsum, 0, 64 * sizeof(float), stream);
    k_fold0<<<1, 256, 0, stream>>>(Wglob, bglob, Wroute, broute, bspat, btemp, bsync, Gfull, cb0);
    k_fold<<<9, 256, 0, stream>>>(Wspat, Wtemp, Wsync, Wroute, Gfull, QcatT, A2F);
    k_main<<<1536, 256, 0, stream>>>(xt, xa, xv, QcatT, accsum, qp);
    k_const<<<8, 256, 0, stream>>>(xt, xa, xv, accsum, A2F, cb0, constb);
    k_add<<<128, 256, 0, stream>>>(qp, constb, out);
}

// Round 5
// 213.756 us; speedup vs baseline: 2.8805x; 1.6222x over previous
//
#include <hip/hip_runtime.h>

#define DIM 768
#define TD 2304
#define NB 8
#define NS 4096
#define NE 6

// ws layout (float offsets)
#define OFF_QCATT  0        // [3][18][768] = 41472  rows: 0-5 Q, 6-11 P, 12-17 A1 (colmean fold)
#define OFF_A2F    41472    // [2304][6]   = 13824   delta-mean fold
#define OFF_GFULL  55296    // [224][6]
#define OFF_CB0    56640    // [16]
#define OFF_ACCSUM 56656    // [8][6] + pad = 64
#define OFF_CONSTB 56720    // [8][6] + pad
#define OFF_QP     56832    // [3][32768][12] = 1179648

// ---------------- kernel A: fold global path (Gfull, cb0) ----------------
__global__ __launch_bounds__(256) void k_fold0(
    const float* __restrict__ Wglob, const float* __restrict__ bglob,
    const float* __restrict__ Wroute, const float* __restrict__ broute,
    const float* __restrict__ bspat, const float* __restrict__ btemp,
    const float* __restrict__ bsync,
    float* __restrict__ Gfull, float* __restrict__ cb0)
{
    __shared__ float lwr[288 * NE];
    __shared__ float lgf[224 * NE];
    const int t = threadIdx.x;
    for (int i = t; i < 288 * NE; i += 256) lwr[i] = Wroute[i];
    __syncthreads();
    if (t < 224) {
        float g[NE] = {0, 0, 0, 0, 0, 0};
        for (int o = 0; o < 64; ++o) {
            const float w = Wglob[t * 64 + o];
            #pragma unroll
            for (int e = 0; e < NE; ++e) g[e] += w * lwr[(224 + o) * NE + e];
        }
        #pragma unroll
        for (int e = 0; e < NE; ++e) { Gfull[t * NE + e] = g[e]; lgf[t * NE + e] = g[e]; }
    }
    __syncthreads();
    if (t < NE) {
        float a = broute[t];
        for (int o = 0; o < 64; ++o)  a += bglob[o] * lwr[(224 + o) * NE + t];
        for (int o = 0; o < 128; ++o) a += bspat[o] * (lwr[o * NE + t] + lgf[o * NE + t]);
        for (int o = 0; o < 64; ++o)  a += btemp[o] * (lwr[(128 + o) * NE + t] + lgf[(128 + o) * NE + t]);
        for (int o = 0; o < 32; ++o)  a += bsync[o] * (lwr[(192 + o) * NE + t] + lgf[(192 + o) * NE + t]);
        cb0[t] = a;
    }
}

// ---------------- kernel B: fold per-column coefficients ----------------
__global__ __launch_bounds__(256) void k_fold(
    const float* __restrict__ Wspat, const float* __restrict__ Wtemp,
    const float* __restrict__ Wsync, const float* __restrict__ Wroute,
    const float* __restrict__ Gfull,
    float* __restrict__ QcatT, float* __restrict__ A2F)
{
    __shared__ float lwr[224 * NE];
    __shared__ float lgf[224 * NE];
    const int t = threadIdx.x;
    for (int i = t; i < 224 * NE; i += 256) { lwr[i] = Wroute[i]; lgf[i] = Gfull[i]; }
    __syncthreads();
    const int d = blockIdx.x * 256 + t;          // exactly 2304 threads
    const int st = d / DIM, dd = d - st * DIM;

    float p[NE] = {0, 0, 0, 0, 0, 0}, a2[NE] = {0, 0, 0, 0, 0, 0};
    for (int o = 0; o < 64; ++o) {
        const float w = Wtemp[d * 64 + o];
        #pragma unroll
        for (int e = 0; e < NE; ++e) {
            p[e]  += w * lwr[(128 + o) * NE + e];
            a2[e] += w * lgf[(128 + o) * NE + e];
        }
    }
    float qq[NE], a1[NE];
    #pragma unroll
    for (int e = 0; e < NE; ++e) { qq[e] = p[e]; a1[e] = 0.f; }
    for (int o = 0; o < 128; ++o) {
        const float w = Wspat[d * 128 + o];
        #pragma unroll
        for (int e = 0; e < NE; ++e) {
            qq[e] += w * lwr[o * NE + e];
            a1[e] += w * lgf[o * NE + e];
        }
    }
    if (st != 0) {
        const float sg = (st == 1) ? 1.f : -1.f;
        for (int o = 0; o < 32; ++o) {
            const float w = sg * Wsync[dd * 32 + o];
            #pragma unroll
            for (int e = 0; e < NE; ++e) {
                qq[e] += w * lwr[(192 + o) * NE + e];
                a1[e] += w * lgf[(192 + o) * NE + e];
            }
        }
    }
    #pragma unroll
    for (int e = 0; e < NE; ++e) {
        QcatT[(st * 18 + e) * DIM + dd]      = qq[e];
        QcatT[(st * 18 + 6 + e) * DIM + dd]  = p[e];
        QcatT[(st * 18 + 12 + e) * DIM + dd] = a1[e];
        A2F[d * NE + e] = a2[e];
    }
}

// ---------------- kernel C: main streaming pass ----------------
// grid = 8b * 3st * 32rblk = 768 blocks; 256 thr = 4 waves = 2 wave-pairs.
// Wave pair covers 64 rows; within a pair, wave h=0 computes Q rows 0-5,
// h=1 computes P rows 6-11 (same x rows, L1-shared). Lane owns 3 fixed
// col-quads {4l, 4l+256, 4l+512}; 18 coef float4 live in registers for the
// whole kernel. Hot loop: 3 coalesced 1KB x-loads + 72 FMA + shfl-reduce.

#define LDR(B0, B1, B2, R) {                        \
    const float* xp_ = xbase + (R) * DIM;           \
    B0 = *(const float4*)(xp_);                     \
    B1 = *(const float4*)(xp_ + 256);               \
    B2 = *(const float4*)(xp_ + 512); }

#define DOT3(QV, B0, B1, B2, C0, C1, C2)                                    \
    QV += B0.x * C0.x; QV += B0.y * C0.y; QV += B0.z * C0.z; QV += B0.w * C0.w; \
    QV += B1.x * C1.x; QV += B1.y * C1.y; QV += B1.z * C1.z; QV += B1.w * C1.w; \
    QV += B2.x * C2.x; QV += B2.y * C2.y; QV += B2.z * C2.z; QV += B2.w * C2.w;

#define RED64(V)                    \
    V += __shfl_xor(V, 1, 64);      \
    V += __shfl_xor(V, 2, 64);      \
    V += __shfl_xor(V, 4, 64);      \
    V += __shfl_xor(V, 8, 64);      \
    V += __shfl_xor(V, 16, 64);     \
    V += __shfl_xor(V, 32, 64);

#define CMP(B0, B1, B2, R) {                                \
    float q0 = 0, q1 = 0, q2 = 0, q3 = 0, q4 = 0, q5 = 0;   \
    DOT3(q0, B0, B1, B2, c00, c01, c02)                     \
    DOT3(q1, B0, B1, B2, c10, c11, c12)                     \
    DOT3(q2, B0, B1, B2, c20, c21, c22)                     \
    DOT3(q3, B0, B1, B2, c30, c31, c32)                     \
    DOT3(q4, B0, B1, B2, c40, c41, c42)                     \
    DOT3(q5, B0, B1, B2, c50, c51, c52)                     \
    cs0 += B0.x; cs1 += B0.y; cs2  += B0.z; cs3  += B0.w;   \
    cs4 += B1.x; cs5 += B1.y; cs6  += B1.z; cs7  += B1.w;   \
    cs8 += B2.x; cs9 += B2.y; cs10 += B2.z; cs11 += B2.w;   \
    RED64(q0) RED64(q1) RED64(q2)                           \
    RED64(q3) RED64(q4) RED64(q5)                           \
    if (l == 0) {                                           \
        float* dst_ = qpb + (R) * 12;                       \
        *(float2*)(dst_ + 0) = make_float2(q0, q1);         \
        *(float2*)(dst_ + 2) = make_float2(q2, q3);         \
        *(float2*)(dst_ + 4) = make_float2(q4, q5);         \
    } }

#define GDOT(GV, C0, C1, C2)                                \
    GV += cs0 * C0.x; GV += cs1 * C0.y; GV += cs2  * C0.z; GV += cs3  * C0.w; \
    GV += cs4 * C1.x; GV += cs5 * C1.y; GV += cs6  * C1.z; GV += cs7  * C1.w; \
    GV += cs8 * C2.x; GV += cs9 * C2.y; GV += cs10 * C2.z; GV += cs11 * C2.w;

__global__ __launch_bounds__(256, 3) void k_main(
    const float* __restrict__ xt, const float* __restrict__ xa, const float* __restrict__ xv,
    const float* __restrict__ QcatT, float* __restrict__ accsum, float* __restrict__ qp)
{
    const int t = threadIdx.x;
    const int w = t >> 6, l = t & 63;
    const int h = w & 1;                 // 0: Q half, 1: P half
    const int pr = w >> 1;               // wave pair -> 64-row slice
    const int bid = blockIdx.x;
    const int rblk = bid & 31;
    const int st = (bid >> 5) % 3;
    const int bb = bid / 96;

    const float* X = (st == 0) ? xt : ((st == 1) ? xa : xv);
    const int row0 = rblk * 128 + pr * 64;
    const float* xbase = X + (size_t)(bb * NS + row0) * DIM + l * 4;
    const float* cqb   = QcatT + (st * 18 + h * 6) * DIM + l * 4;
    float*       qpb   = qp + ((size_t)(st * NB + bb) * NS + row0) * 12 + h * 6;

    // coefficient registers (resident for whole kernel): c[e][k]
    float4 c00 = *(const float4*)(cqb + 0 * DIM + 0);
    float4 c01 = *(const float4*)(cqb + 0 * DIM + 256);
    float4 c02 = *(const float4*)(cqb + 0 * DIM + 512);
    float4 c10 = *(const float4*)(cqb + 1 * DIM + 0);
    float4 c11 = *(const float4*)(cqb + 1 * DIM + 256);
    float4 c12 = *(const float4*)(cqb + 1 * DIM + 512);
    float4 c20 = *(const float4*)(cqb + 2 * DIM + 0);
    float4 c21 = *(const float4*)(cqb + 2 * DIM + 256);
    float4 c22 = *(const float4*)(cqb + 2 * DIM + 512);
    float4 c30 = *(const float4*)(cqb + 3 * DIM + 0);
    float4 c31 = *(const float4*)(cqb + 3 * DIM + 256);
    float4 c32 = *(const float4*)(cqb + 3 * DIM + 512);
    float4 c40 = *(const float4*)(cqb + 4 * DIM + 0);
    float4 c41 = *(const float4*)(cqb + 4 * DIM + 256);
    float4 c42 = *(const float4*)(cqb + 4 * DIM + 512);
    float4 c50 = *(const float4*)(cqb + 5 * DIM + 0);
    float4 c51 = *(const float4*)(cqb + 5 * DIM + 256);
    float4 c52 = *(const float4*)(cqb + 5 * DIM + 512);

    // per-lane column sums (for the global colmean path)
    float cs0 = 0, cs1 = 0, cs2 = 0, cs3 = 0, cs4 = 0, cs5 = 0;
    float cs6 = 0, cs7 = 0, cs8 = 0, cs9 = 0, cs10 = 0, cs11 = 0;

    float4 xA0, xA1, xA2, xB0, xB1, xB2;
    LDR(xA0, xA1, xA2, 0)
    LDR(xB0, xB1, xB2, 1)

    for (int r = 0; r < 64; r += 2) {
        CMP(xA0, xA1, xA2, r)
        if (r + 2 < 64) { LDR(xA0, xA1, xA2, r + 2) }
        CMP(xB0, xB1, xB2, r + 1)
        if (r + 3 < 64) { LDR(xB0, xB1, xB2, r + 3) }
    }

    // global-path: dot colsums with A1 coefs (rows 12 + h*3 + e2), reduce, atomic
    const float* cab = QcatT + (st * 18 + 12 + h * 3) * DIM + l * 4;
    const float4 A00 = *(const float4*)(cab + 0 * DIM + 0);
    const float4 A01 = *(const float4*)(cab + 0 * DIM + 256);
    const float4 A02 = *(const float4*)(cab + 0 * DIM + 512);
    const float4 A10 = *(const float4*)(cab + 1 * DIM + 0);
    const float4 A11 = *(const float4*)(cab + 1 * DIM + 256);
    const float4 A12 = *(const float4*)(cab + 1 * DIM + 512);
    const float4 A20 = *(const float4*)(cab + 2 * DIM + 0);
    const float4 A21 = *(const float4*)(cab + 2 * DIM + 256);
    const float4 A22 = *(const float4*)(cab + 2 * DIM + 512);

    float g0 = 0, g1 = 0, g2 = 0;
    GDOT(g0, A00, A01, A02)
    GDOT(g1, A10, A11, A12)
    GDOT(g2, A20, A21, A22)
    RED64(g0) RED64(g1) RED64(g2)
    if (l == 0) {
        atomicAdd(&accsum[bb * NE + h * 3 + 0], g0);
        atomicAdd(&accsum[bb * NE + h * 3 + 1], g1);
        atomicAdd(&accsum[bb * NE + h * 3 + 2], g2);
    }
}

// ---------------- kernel D: per-batch global constant ----------------
__global__ __launch_bounds__(256) void k_const(
    const float* __restrict__ xt, const float* __restrict__ xa, const float* __restrict__ xv,
    const float* __restrict__ accsum, const float* __restrict__ A2F,
    const float* __restrict__ cb0, float* __restrict__ constb)
{
    const int b = blockIdx.x, t = threadIdx.x;
    const float* Xs[3] = { xt, xa, xv };
    float acc[NE] = {0, 0, 0, 0, 0, 0};
    for (int f = t; f < TD; f += 256) {
        const int st = f / DIM, dd = f - st * DIM;
        const float* Xp = Xs[st] + (size_t)b * NS * DIM;
        const float dm = Xp[(size_t)(NS - 1) * DIM + dd] - Xp[dd];
        const float* Ap = A2F + f * NE;
        #pragma unroll
        for (int e = 0; e < NE; ++e) acc[e] += dm * Ap[e];
    }
    #pragma unroll
    for (int e = 0; e < NE; ++e)
        for (int m = 1; m < 64; m <<= 1) acc[e] += __shfl_xor(acc[e], m, 64);
    __shared__ float wred[4][NE];
    if ((t & 63) == 0) {
        #pragma unroll
        for (int e = 0; e < NE; ++e) wred[t >> 6][e] = acc[e];
    }
    __syncthreads();
    if (t < NE) {
        const float inv = 1.f / 4096.f;
        const float dsum = wred[0][t] + wred[1][t] + wred[2][t] + wred[3][t];
        constb[b * NE + t] = cb0[t] + accsum[b * NE + t] * inv + dsum * inv;
    }
}

// ---------------- kernel E: combine q - shifted p + const ----------------
__global__ __launch_bounds__(256) void k_add(
    const float* __restrict__ qp, const float* __restrict__ constb, float* __restrict__ out)
{
    const int row = blockIdx.x * 256 + threadIdx.x;   // 32768 rows exact
    const int b = row >> 12, s = row & (NS - 1);
    const int rowp = (s == 0) ? row : row - 1;
    float o[NE];
    #pragma unroll
    for (int e = 0; e < NE; ++e) o[e] = constb[b * NE + e];
    #pragma unroll
    for (int st = 0; st < 3; ++st) {
        const float* qr = qp + ((size_t)st * NB * NS + row) * 12;
        const float* pr = qp + ((size_t)st * NB * NS + rowp) * 12;
        #pragma unroll
        for (int e = 0; e < NE; ++e) o[e] += qr[e] - pr[6 + e];
    }
    float* op = out + (size_t)row * NE;
    #pragma unroll
    for (int e = 0; e < NE; ++e) op[e] = o[e];
}

extern "C" void kernel_launch(void* const* d_in, const int* in_sizes, int n_in,
                              void* d_out, int out_size, void* d_ws, size_t ws_size,
                              hipStream_t stream)
{
    const float* xt     = (const float*)d_in[0];
    const float* xa     = (const float*)d_in[1];
    const float* xv     = (const float*)d_in[2];
    const float* Wspat  = (const float*)d_in[3];
    const float* bspat  = (const float*)d_in[4];
    const float* Wtemp  = (const float*)d_in[5];
    const float* btemp  = (const float*)d_in[6];
    const float* Wsync  = (const float*)d_in[7];
    const float* bsync  = (const float*)d_in[8];
    const float* Wglob  = (const float*)d_in[9];
    const float* bglob  = (const float*)d_in[10];
    const float* Wroute = (const float*)d_in[11];
    const float* broute = (const float*)d_in[12];
    float* out = (float*)d_out;

    float* ws     = (float*)d_ws;
    float* QcatT  = ws + OFF_QCATT;
    float* A2F    = ws + OFF_A2F;
    float* Gfull  = ws + OFF_GFULL;
    float* cb0    = ws + OFF_CB0;
    float* accsum = ws + OFF_ACCSUM;
    float* constb = ws + OFF_CONSTB;
    float* qp     = ws + OFF_QP;

    hipMemsetAsync(accsum, 0, 64 * sizeof(float), stream);
    k_fold0<<<1, 256, 0, stream>>>(Wglob, bglob, Wroute, broute, bspat, btemp, bsync, Gfull, cb0);
    k_fold<<<9, 256, 0, stream>>>(Wspat, Wtemp, Wsync, Wroute, Gfull, QcatT, A2F);
    k_main<<<768, 256, 0, stream>>>(xt, xa, xv, QcatT, accsum, qp);
    k_const<<<8, 256, 0, stream>>>(xt, xa, xv, accsum, A2F, cb0, constb);
    k_add<<<128, 256, 0, stream>>>(qp, constb, out);
}